// Round 16
// baseline (7637.008 us; speedup 1.0000x reference)
//
#include <hip/hip_runtime.h>
#include <hip/hip_fp16.h>

// out[i] = state[i]*W[0] + neighbor_sum[i]*W[1] + b
// neighbor_sum[dst] += state[src] over 32M edges.
//
// MEASURED (R8..R15): partition ~200-216us (VALU/VMEM-bound) and bins ~176us
// (LDS-atomic-bound at ~3.3cyc/lane) are independent pipe-disjoint walls;
// serialized they pin the total at ~383us. This round FUSES them into one
// kernel with producer/consumer BLOCK roles running CONCURRENTLY:
//   producers (512 blocks): R15 ballot-multisplit partition of 4096-edge
//     tiles into 64 bucket runs, written to TILE-PRIVATE slabs (no shared
//     cursors -> no holes) via agent-scope stores (L3-visible cross-XCD),
//     per-tile header (run offset|count), then done[t] release flag.
//   consumers (496 blocks = 62 buckets x 2 halves x 4 tile-classes):
//     spin-acquire done[t], read their bucket's run, filter by half bit,
//     ds_add_f32 into 32KB LDS bins; write partial at the end.
// Deadlock-free without cooperative launch: consumers (496) < minimum
// residency (>=512 blocks at 2/CU; expected 4/CU = 1024), so producers
// always have slots and make progress.

#define NB_SHIFT 14
#define RANGE    (1 << NB_SHIFT)       // 16384 nodes per bucket
#define HALF_SH  13
#define HRANGE   8192                  // nodes per consumer half-bucket
#define NBALL    64
#define HPITCH   (NBALL + 1)           // padded hist pitch
#define TPB      512
#define IPT      8
#define TILE     (TPB * IPT)           // 4096 edges per tile
#define NWAVES   (TPB / 64)            // 8
#define NGRP     (IPT * NWAVES)        // 64 rank groups per tile
#define TCLASS   4
#define SLABSZ   (TILE + NBALL)        // 4160 record slots per tile slab
#define NCONS    496                   // 62 * 2 * 4
#define NPROD    512

typedef int   iv4 __attribute__((ext_vector_type(4)));
typedef float fv4 __attribute__((ext_vector_type(4)));

// Native LDS float atomic add (no return); low 32 bits of generic ptr = DS offset.
__device__ __forceinline__ void lds_fadd(float* p, float v) {
    unsigned addr = (unsigned)(uintptr_t)p;
    asm volatile("ds_add_f32 %0, %1" :: "v"(addr), "v"(v));
}
// Drain this wave's asm DS ops before a barrier (compiler can't track them).
__device__ __forceinline__ void lds_drain() {
    asm volatile("s_waitcnt lgkmcnt(0)" ::: "memory");
    __builtin_amdgcn_sched_barrier(0);
}

// ---------------- zero done flags ----------------
__global__ __launch_bounds__(256) void k_zero_done(int* __restrict__ done, int tiles) {
    int i = blockIdx.x * blockDim.x + threadIdx.x;
    int stride = gridDim.x * blockDim.x;
    for (; i < tiles; i += stride) done[i] = 0;
}

// ---------------- state -> f16 table ----------------
__global__ __launch_bounds__(256) void k_cvt(const float* __restrict__ state,
                                             unsigned short* __restrict__ sh, int n4) {
    int i = blockIdx.x * blockDim.x + threadIdx.x;
    if (i >= n4) return;
    fv4 v = *(const fv4*)(state + i * 4);
    ushort4 h;
    h.x = __half_as_ushort(__float2half_rn(v[0]));
    h.y = __half_as_ushort(__float2half_rn(v[1]));
    h.z = __half_as_ushort(__float2half_rn(v[2]));
    h.w = __half_as_ushort(__float2half_rn(v[3]));
    *(ushort4*)(sh + i * 4) = h;
}

// ---------------- fused producer/consumer ----------------
// smem union: producer {hist 16640B, stage 16640B, sbase 256, sbase2 256,
// totals 256} = 34048B; consumer {bins 32768B}.
__global__ __launch_bounds__(TPB, 8) void k_fused(
    const unsigned short* __restrict__ sh,
    const int* __restrict__ src,
    const int* __restrict__ dst,
    unsigned* __restrict__ slabs,     // [tiles][SLABSZ]
    int* __restrict__ header,         // [tiles][64]  (sbase2<<16)|cnt
    int* __restrict__ done,           // [tiles]
    float* __restrict__ partial,      // [NCONS][HRANGE]
    int n_edges, int tiles)
{
    __shared__ __align__(16) unsigned char smem[34048];
    const int bid = blockIdx.x;
    const int tid = threadIdx.x;
    const int wid = tid >> 6, lane = tid & 63;

    if (bid < NCONS) {
        // ================= CONSUMER =================
        float* bins = (float*)smem;                   // 32KB
        const int b  = bid >> 3;
        const int h  = (bid >> 2) & 1;
        const int tc = bid & 3;

        fv4* bins4 = (fv4*)bins;
        for (int i = tid; i < HRANGE / 4; i += TPB)
            bins4[i] = (fv4){0.f, 0.f, 0.f, 0.f};
        __syncthreads();

        for (int i = wid; ; i += NWAVES) {
            const int t = tc + 4 * i;
            if (t >= tiles) break;
            // wait tile published (all lanes load same addr -> broadcast)
            while (__hip_atomic_load(&done[t], __ATOMIC_ACQUIRE,
                                     __HIP_MEMORY_SCOPE_AGENT) == 0)
                __builtin_amdgcn_s_sleep(2);
            const int hdr = __hip_atomic_load(&header[t * NBALL + b],
                                              __ATOMIC_RELAXED, __HIP_MEMORY_SCOPE_AGENT);
            const int cnt = hdr & 0xFFFF;
            if (cnt == 0) continue;
            const int sb2 = hdr >> 16;                // even
            const int pairs = (cnt + 1) >> 1;
            const unsigned long long* base =
                (const unsigned long long*)(slabs + (size_t)t * SLABSZ + sb2);
            for (int j = lane; j < pairs; j += 64) {
                unsigned long long pr = __hip_atomic_load(base + j,
                        __ATOMIC_RELAXED, __HIP_MEMORY_SCOPE_AGENT);
                unsigned r0 = (unsigned)pr;
                unsigned r1 = (unsigned)(pr >> 32);   // pad slot = 0 -> +0.0 to h=0 bin 0
                int l0 = r0 & (RANGE - 1);
                int l1 = r1 & (RANGE - 1);
                if ((l0 >> HALF_SH) == h)
                    lds_fadd(&bins[l0 & (HRANGE - 1)],
                             __half2float(__ushort_as_half((unsigned short)(r0 >> NB_SHIFT))));
                if ((l1 >> HALF_SH) == h)
                    lds_fadd(&bins[l1 & (HRANGE - 1)],
                             __half2float(__ushort_as_half((unsigned short)(r1 >> NB_SHIFT))));
            }
        }
        lds_drain();
        __syncthreads();
        float* p = partial + (size_t)bid * HRANGE;
        for (int i = tid; i < HRANGE / 4; i += TPB)
            *((fv4*)p + i) = bins4[i];
        return;
    }

    // ================= PRODUCER =================
    int*      hist   = (int*)smem;                        // [NGRP*HPITCH]
    unsigned* stage  = (unsigned*)(smem + 16640);         // [SLABSZ]
    int*      sbase  = (int*)(smem + 33280);              // [64] raw-cnt prefix
    int*      sbase2 = (int*)(smem + 33536);              // [64] even-padded prefix
    int*      totals = (int*)(smem + 33792);              // [64]

    const int pid = bid - NCONS;
    for (int t = pid; t < tiles; t += NPROD) {
        // zero hist
        for (int i = tid; i < NGRP * HPITCH; i += TPB) hist[i] = 0;

        const long long e0 = (long long)t * TILE + (long long)tid * IPT;
        unsigned rec[IPT];
        int bk[IPT];
        int rank[IPT];

        if (e0 + IPT <= (long long)n_edges) {
            const long long i4 = e0 >> 2;
            iv4 sA = __builtin_nontemporal_load((const iv4*)src + i4);
            iv4 sB = __builtin_nontemporal_load((const iv4*)src + i4 + 1);
            iv4 dA = __builtin_nontemporal_load((const iv4*)dst + i4);
            iv4 dB = __builtin_nontemporal_load((const iv4*)dst + i4 + 1);
            int s[IPT] = { sA[0], sA[1], sA[2], sA[3], sB[0], sB[1], sB[2], sB[3] };
            int d[IPT] = { dA[0], dA[1], dA[2], dA[3], dB[0], dB[1], dB[2], dB[3] };
            unsigned v[IPT];
            #pragma unroll
            for (int k = 0; k < IPT; ++k) v[k] = sh[s[k]];
            #pragma unroll
            for (int k = 0; k < IPT; ++k) {
                bk[k]  = d[k] >> NB_SHIFT;
                rec[k] = (v[k] << NB_SHIFT) | (unsigned)(d[k] & (RANGE - 1));
            }
        } else {
            #pragma unroll
            for (int k = 0; k < IPT; ++k) {
                long long e = e0 + k;
                if (e < n_edges) {
                    int d = dst[e];
                    unsigned v = sh[src[e]];
                    bk[k]  = d >> NB_SHIFT;
                    rec[k] = (v << NB_SHIFT) | (unsigned)(d & (RANGE - 1));
                } else {
                    bk[k] = -1; rec[k] = 0;
                }
            }
        }
        __syncthreads();   // hist zeroed

        // ballot multi-split rank (atomic-free)
        #pragma unroll
        for (int k = 0; k < IPT; ++k) {
            const int b = bk[k];
            unsigned long long m = __ballot(b >= 0);
            #pragma unroll
            for (int j = 0; j < 6; ++j) {
                unsigned long long bl = __ballot((b >> j) & 1);
                m &= ((b >> j) & 1) ? bl : ~bl;
            }
            int r = __builtin_amdgcn_mbcnt_hi((unsigned)(m >> 32),
                    __builtin_amdgcn_mbcnt_lo((unsigned)m, 0));
            rank[k] = r;
            if (b >= 0 && r == 0)
                hist[(k * NWAVES + wid) * HPITCH + b] = (int)__popcll(m);
        }
        __syncthreads();

        // scan1: per-bucket exclusive scan over 64 groups
        #pragma unroll
        for (int bb = 0; bb < NBALL / NWAVES; ++bb) {
            const int b = wid * (NBALL / NWAVES) + bb;
            int v = hist[lane * HPITCH + b];
            int incl = v;
            #pragma unroll
            for (int off = 1; off < 64; off <<= 1) {
                int u = __shfl_up(incl, off);
                if (lane >= off) incl += u;
            }
            hist[lane * HPITCH + b] = incl - v;
            if (lane == 63) totals[b] = incl;
        }
        __syncthreads();

        // scan2 (wave 0): packed prefix of (he<<16 | cnt); write header
        if (tid < NBALL) {
            int cnt = totals[tid];
            int he  = (cnt + 1) & ~1;
            int pk  = (he << 16) | cnt;
            int v = pk;
            #pragma unroll
            for (int off = 1; off < 64; off <<= 1) {
                int u = __shfl_up(v, off);
                if (tid >= off) v += u;
            }
            int excl = v - pk;
            sbase[tid]  = excl & 0xFFFF;
            sbase2[tid] = excl >> 16;
            __hip_atomic_store(&header[t * NBALL + tid],
                               ((excl >> 16) << 16) | cnt,
                               __ATOMIC_RELAXED, __HIP_MEMORY_SCOPE_AGENT);
        }
        __syncthreads();

        // phase C: bucket-ordered scatter into stage
        #pragma unroll
        for (int k = 0; k < IPT; ++k)
            if (bk[k] >= 0) {
                int b = bk[k];
                stage[sbase[b] + hist[(k * NWAVES + wid) * HPITCH + b] + rank[k]] = rec[k];
            }
        __syncthreads();

        // phase D: per-wave bucket runs -> slab via agent 8B stores
        unsigned* slabT = slabs + (size_t)t * SLABSZ;
        for (int b = wid; b < NBALL; b += NWAVES) {
            const int cnt = totals[b];
            if (cnt == 0) continue;
            const int sb = sbase[b], sb2 = sbase2[b];
            const int pairs = (cnt + 1) >> 1;
            unsigned long long* dstp = (unsigned long long*)(slabT + sb2);
            for (int j = lane; j < pairs; j += 64) {
                unsigned lo = stage[sb + 2 * j];
                unsigned hi = (2 * j + 1 < cnt) ? stage[sb + 2 * j + 1] : 0u;
                unsigned long long pr = (unsigned long long)lo |
                                        ((unsigned long long)hi << 32);
                __hip_atomic_store(dstp + j, pr,
                                   __ATOMIC_RELAXED, __HIP_MEMORY_SCOPE_AGENT);
            }
        }
        __syncthreads();   // drains all waves' stores (vmcnt(0) before barrier)

        if (tid == 0)
            __hip_atomic_store(&done[t], 1,
                               __ATOMIC_RELEASE, __HIP_MEMORY_SCOPE_AGENT);
    }
}

// ---------------- finalize: out = W0*state + W1*sum_4(partial) + b ---------
__global__ __launch_bounds__(256) void k_finalize(
    const float* __restrict__ state,
    const float* __restrict__ partial,
    const float* __restrict__ W,
    const float* __restrict__ bias,
    float* __restrict__ out, int n)
{
    const int i = (blockIdx.x * blockDim.x + threadIdx.x) * 4;
    if (i >= n) return;
    const int b   = i >> NB_SHIFT;
    const int h   = (i >> HALF_SH) & 1;
    const int loc = i & (HRANGE - 1);
    const float* pb = partial + ((size_t)(b * 8 + h * 4)) * HRANGE + loc;
    fv4 s = {0.f, 0.f, 0.f, 0.f};
    #pragma unroll
    for (int tc = 0; tc < TCLASS; ++tc)
        s += *(const fv4*)(pb + (size_t)tc * HRANGE);
    const float w0 = W[0], w1 = W[1], bb = bias[0];
    fv4 st = *(const fv4*)(state + i);
    fv4 o;
    #pragma unroll
    for (int k = 0; k < 4; ++k) o[k] = fmaf(st[k], w0, fmaf(s[k], w1, bb));
    *(fv4*)(out + i) = o;
}

// ---------------- fallback (ws too small): atomic scatter ----------------
__global__ __launch_bounds__(256) void gnn_zero(float4* __restrict__ ws, int n4) {
    int i = blockIdx.x * blockDim.x + threadIdx.x;
    int stride = gridDim.x * blockDim.x;
    const float4 z = make_float4(0.f, 0.f, 0.f, 0.f);
    for (; i < n4; i += stride) ws[i] = z;
}

__global__ __launch_bounds__(256) void gnn_scatter_dev(const float* __restrict__ state,
                                                       const int* __restrict__ src,
                                                       const int* __restrict__ dst,
                                                       float* __restrict__ nsum,
                                                       int n_edges) {
    const int tid = blockIdx.x * blockDim.x + threadIdx.x;
    const int stride = gridDim.x * blockDim.x;
    const int n4 = n_edges >> 2;
    const int4* __restrict__ src4 = (const int4*)src;
    const int4* __restrict__ dst4 = (const int4*)dst;
    for (int i = tid; i < n4; i += stride) {
        int4 s = src4[i];
        int4 d = dst4[i];
        atomicAdd(&nsum[d.x], state[s.x]);
        atomicAdd(&nsum[d.y], state[s.y]);
        atomicAdd(&nsum[d.z], state[s.z]);
        atomicAdd(&nsum[d.w], state[s.w]);
    }
    for (int i = (n4 << 2) + tid; i < n_edges; i += stride)
        atomicAdd(&nsum[dst[i]], state[src[i]]);
}

__global__ __launch_bounds__(256) void gnn_finalize_flat(const float* __restrict__ state,
                                                         const float* __restrict__ nsum,
                                                         const float* __restrict__ W,
                                                         const float* __restrict__ b,
                                                         float* __restrict__ out, int n) {
    int i = blockIdx.x * blockDim.x + threadIdx.x;
    if (i < n) out[i] = fmaf(state[i], W[0], fmaf(nsum[i], W[1], b[0]));
}

extern "C" void kernel_launch(void* const* d_in, const int* in_sizes, int n_in,
                              void* d_out, int out_size, void* d_ws, size_t ws_size,
                              hipStream_t stream) {
    const float* state = (const float*)d_in[0];
    const int*   esrc  = (const int*)d_in[1];
    const int*   edst  = (const int*)d_in[2];
    const float* W     = (const float*)d_in[3];
    const float* b     = (const float*)d_in[4];
    float* out = (float*)d_out;

    const int n_nodes = in_sizes[0];   // 1,000,000
    const int n_edges = in_sizes[1];   // 32,000,000
    const int tiles   = (n_edges + TILE - 1) / TILE;   // 7813

    const size_t shOff    = 0;
    const size_t shBytes  = (((size_t)n_nodes * 2) + 255) & ~(size_t)255;
    const size_t slabOff  = shBytes;
    const size_t slabBytes= (((size_t)tiles * SLABSZ * 4) + 255) & ~(size_t)255;
    const size_t hdrOff   = slabOff + slabBytes;
    const size_t hdrBytes = (((size_t)tiles * NBALL * 4) + 255) & ~(size_t)255;
    const size_t doneOff  = hdrOff + hdrBytes;
    const size_t doneBytes= (((size_t)tiles * 4) + 255) & ~(size_t)255;
    const size_t parOff   = doneOff + doneBytes;
    const size_t parBytes = (size_t)NCONS * HRANGE * sizeof(float);
    const size_t need     = parOff + parBytes;          // ~148.5 MB

    if (ws_size >= need && (n_nodes & 3) == 0 && (n_edges & 3) == 0 &&
        n_nodes <= 62 * RANGE) {
        unsigned short* sh = (unsigned short*)((char*)d_ws + shOff);
        unsigned* slabs    = (unsigned*)((char*)d_ws + slabOff);
        int*      header   = (int*)((char*)d_ws + hdrOff);
        int*      done     = (int*)((char*)d_ws + doneOff);
        float*    partial  = (float*)((char*)d_ws + parOff);

        k_zero_done<<<32, 256, 0, stream>>>(done, tiles);
        k_cvt<<<(n_nodes / 4 + 255) / 256, 256, 0, stream>>>(state, sh, n_nodes / 4);

        k_fused<<<NCONS + NPROD, TPB, 0, stream>>>(sh, esrc, edst,
                                                   slabs, header, done, partial,
                                                   n_edges, tiles);

        int blocks = (n_nodes / 4 + 255) / 256;
        k_finalize<<<blocks, 256, 0, stream>>>(state, partial, W, b, out, n_nodes);
    } else {
        // fallback: device-scope atomic scatter (needs only 4 MB ws)
        float* nsum = (float*)d_ws;
        int n4n = n_nodes >> 2;
        int zb = (n4n + 255) / 256; if (zb > 2048) zb = 2048;
        gnn_zero<<<zb, 256, 0, stream>>>((float4*)nsum, n4n);
        int work = n_edges >> 2;
        int sb = (work + 255) / 256; if (sb > 8192) sb = 8192;
        gnn_scatter_dev<<<sb, 256, 0, stream>>>(state, esrc, edst, nsum, n_edges);
        int fb = (n_nodes + 255) / 256;
        gnn_finalize_flat<<<fb, 256, 0, stream>>>(state, nsum, W, b, out, n_nodes);
    }
}

// Round 17
// 380.499 us; speedup vs baseline: 20.0710x; 20.0710x over previous
//
#include <hip/hip_runtime.h>
#include <hip/hip_fp16.h>

// out[i] = state[i]*W[0] + neighbor_sum[i]*W[1] + b
// neighbor_sum[dst] += state[src] over 32M edges.
//
// REVERT to best-measured configuration (R11, 380.9us). Session evidence:
//  - global fp32 atomics: ~20.8 Gops/s regardless of scope (R1/R2) -> binning.
//  - LDS atomics (flat OR native ds): ~3.3 cyc/lane; 32M ops ~ 170us (R9/R12).
//  - atomic-free ballot ranking (R15): 216us — SLOWER than LDS-atomic rank.
//  - producer/consumer fusion (R16): 20x regression (agent-scope per-pair
//    memory ops bypass L2). Overlap infeasible in this harness.
// Structure: cvt -> partition (LDS-atomic rank, 200us) -> bins (ds_add_f32,
// ~160us) -> finalize. Four different pipelines converged to 383+-2us; this
// is the practical floor for the two serialized per-edge walls.

#define NB_SHIFT 14
#define RANGE    (1 << NB_SHIFT)       // 16384 nodes per bucket
#define NBALL    64                    // bucket slots (62 used for N=1e6)
#define TPB      512
#define IPT      8
#define TILE     (TPB * IPT)           // 4096 edges per tile
#define NWAVES   (TPB / 64)
#define NREP     4                     // cursor/record-list replicas
#define GSPL     2                     // slices per (bucket,rep) in pass 2
#define BPB      (NREP * GSPL)         // partial slices per bucket = 8

typedef int   iv4 __attribute__((ext_vector_type(4)));
typedef float fv4 __attribute__((ext_vector_type(4)));
typedef unsigned uv4 __attribute__((ext_vector_type(4)));
typedef unsigned uv2 __attribute__((ext_vector_type(2)));

// Native LDS float atomic add (no return). Low 32 bits of a generic pointer
// to LDS are the DS byte offset (apertures are 4GB-aligned on gfx9+).
__device__ __forceinline__ void lds_fadd(float* p, float v) {
    unsigned addr = (unsigned)(uintptr_t)p;
    asm volatile("ds_add_f32 %0, %1" :: "v"(addr), "v"(v) : "memory");
}

// Drain this wave's outstanding DS ops (the compiler does not track the
// inline-asm ds_add_f32; without this, __syncthreads() won't wait for them).
__device__ __forceinline__ void lds_drain() {
    asm volatile("s_waitcnt lgkmcnt(0)" ::: "memory");
    __builtin_amdgcn_sched_barrier(0);
}

// ---------------- pass 0a: init cursors ----------------
__global__ void k_init_cursors(int* __restrict__ cursors) {
    cursors[threadIdx.x] = 0;          // 256 slots
}

// ---------------- pass 0b: state -> f16 table ----------------
__global__ __launch_bounds__(256) void k_cvt(const float* __restrict__ state,
                                             unsigned short* __restrict__ sh, int n4) {
    int i = blockIdx.x * blockDim.x + threadIdx.x;
    if (i >= n4) return;
    fv4 v = *(const fv4*)(state + i * 4);
    ushort4 h;
    h.x = __half_as_ushort(__float2half_rn(v[0]));
    h.y = __half_as_ushort(__float2half_rn(v[1]));
    h.z = __half_as_ushort(__float2half_rn(v[2]));
    h.w = __half_as_ushort(__float2half_rn(v[3]));
    *(ushort4*)(sh + i * 4) = h;
}

// ---------------- pass 1: partition ----------------
__global__ __launch_bounds__(TPB) void k_partition(
    const unsigned short* __restrict__ sh,   // f16 state bits
    const int* __restrict__ src,
    const int* __restrict__ dst,
    unsigned* __restrict__ records,          // [NBALL*NREP][capR]
    int* __restrict__ cursors,               // [NBALL*NREP]
    int n_edges, int capR)
{
    __shared__ unsigned stage[TILE];
    __shared__ int cnt[NBALL];
    __shared__ int sbase[NBALL];
    __shared__ int gbase[NBALL];

    const int tid = threadIdx.x;
    const int rep = blockIdx.x & (NREP - 1);
    if (tid < NBALL) cnt[tid] = 0;

    const long long e0 = (long long)blockIdx.x * TILE + (long long)tid * IPT;

    unsigned rec[IPT];
    int bk[IPT];
    int pos[IPT];

    if (e0 + IPT <= (long long)n_edges) {
        const long long i4 = e0 >> 2;
        iv4 sA = __builtin_nontemporal_load((const iv4*)src + i4);
        iv4 sB = __builtin_nontemporal_load((const iv4*)src + i4 + 1);
        iv4 dA = __builtin_nontemporal_load((const iv4*)dst + i4);
        iv4 dB = __builtin_nontemporal_load((const iv4*)dst + i4 + 1);
        int s[IPT] = { sA[0], sA[1], sA[2], sA[3], sB[0], sB[1], sB[2], sB[3] };
        int d[IPT] = { dA[0], dA[1], dA[2], dA[3], dB[0], dB[1], dB[2], dB[3] };
        unsigned v[IPT];
        #pragma unroll
        for (int k = 0; k < IPT; ++k) v[k] = sh[s[k]];      // 2B random gather
        #pragma unroll
        for (int k = 0; k < IPT; ++k) {
            bk[k]  = d[k] >> NB_SHIFT;
            rec[k] = (v[k] << NB_SHIFT) | (unsigned)(d[k] & (RANGE - 1));
        }
    } else {
        #pragma unroll
        for (int k = 0; k < IPT; ++k) {
            long long e = e0 + k;
            if (e < n_edges) {
                int d = dst[e];
                unsigned v = sh[src[e]];
                bk[k]  = d >> NB_SHIFT;
                rec[k] = (v << NB_SHIFT) | (unsigned)(d & (RANGE - 1));
            } else {
                bk[k] = -1; rec[k] = 0;
            }
        }
    }
    __syncthreads();   // cnt[] zeroed before first atomic

    // phase A: rank within (tile,bucket) — one LDS int atomic per edge
    #pragma unroll
    for (int k = 0; k < IPT; ++k)
        if (bk[k] >= 0) pos[k] = atomicAdd(&cnt[bk[k]], 1);
    __syncthreads();

    // phase B: wave 0 scans counts + reserves EVEN global ranges (replica rep)
    if (tid < NBALL) {
        int h = cnt[tid];
        int v = h;
        #pragma unroll
        for (int off = 1; off < 64; off <<= 1) {
            int u = __shfl_up(v, off);
            if (tid >= off) v += u;
        }
        sbase[tid] = v - h;
        int he = (h + 1) & ~1;                         // even reservation
        gbase[tid] = atomicAdd(&cursors[(tid << 2) | rep], he);
    }
    __syncthreads();

    // phase C: place records bucket-ordered in LDS
    #pragma unroll
    for (int k = 0; k < IPT; ++k)
        if (bk[k] >= 0) stage[sbase[bk[k]] + pos[k]] = rec[k];
    __syncthreads();

    // phase D: per-wave bucket runs — 8B paired stores
    const int wid = tid >> 6, lane = tid & 63;
    for (int b = wid; b < NBALL; b += NWAVES) {
        const int sb = sbase[b], h = cnt[b], gb = gbase[b];
        const int hp = (h + 1) >> 1;                   // pairs (incl. pad)
        unsigned* dstp = records + (size_t)((b << 2) | rep) * capR + gb;
        for (int j = lane; j < hp; j += 64) {
            uv2 r;
            r[0] = stage[sb + 2 * j];
            r[1] = (2 * j + 1 < h) ? stage[sb + 2 * j + 1] : 0u;  // pad: +0.0 to bin 0
            *(uv2*)(dstp + 2 * j) = r;
        }
    }
}

// ---------------- pass 2: per-bucket LDS accumulate ----------------
__global__ __launch_bounds__(1024) void k_bins(
    const unsigned* __restrict__ records,
    const int* __restrict__ cursors,
    float* __restrict__ partial,      // [NBUSED*BPB][RANGE]
    int capR)
{
    __shared__ float bins[RANGE];     // 64 KB
    const int b   = blockIdx.x / BPB;
    const int sub = blockIdx.x % BPB;
    const int rep = sub >> 1;
    const int g   = sub & 1;
    const int cnt = cursors[(b << 2) | rep];          // even
    const size_t base = (size_t)((b << 2) | rep) * capR;
    const int lo = (int)((long long)cnt * g       / GSPL) & ~1;
    const int hi = (g == GSPL - 1) ? cnt : ((int)((long long)cnt * (g + 1) / GSPL) & ~1);
    const int tid = threadIdx.x;

    fv4* bins4 = (fv4*)bins;
    for (int i = tid; i < RANGE / 4; i += 1024) bins4[i] = (fv4){0.f, 0.f, 0.f, 0.f};
    __syncthreads();

    // head: align to 4 records (lo is even)
    int A = (lo + 3) & ~3; if (A > hi) A = hi;
    if (tid < A - lo) {
        unsigned r = records[base + lo + tid];
        float v = __half2float(__ushort_as_half((unsigned short)(r >> NB_SHIFT)));
        lds_fadd(&bins[r & (RANGE - 1)], v);
    }
    // body: uint4 reads
    for (int i = A + tid * 4; i + 4 <= hi; i += 1024 * 4) {
        uv4 r = *(const uv4*)(records + base + i);
        #pragma unroll
        for (int k = 0; k < 4; ++k) {
            float v = __half2float(__ushort_as_half((unsigned short)(r[k] >> NB_SHIFT)));
            lds_fadd(&bins[r[k] & (RANGE - 1)], v);
        }
    }
    // tail
    {
        int start = A + ((hi - A) & ~3);
        if (tid < hi - start) {
            unsigned r = records[base + start + tid];
            float v = __half2float(__ushort_as_half((unsigned short)(r >> NB_SHIFT)));
            lds_fadd(&bins[r & (RANGE - 1)], v);
        }
    }
    lds_drain();       // wait this wave's ds_add_f32s (compiler can't see them)
    __syncthreads();   // then barrier -> all waves' adds landed

    float* p = partial + (size_t)blockIdx.x * RANGE;
    for (int i = tid; i < RANGE / 4; i += 1024)
        *((fv4*)p + i) = bins4[i];
}

// ---------------- pass 3: reduce partials + affine ----------------
__global__ __launch_bounds__(256) void k_finalize(
    const float* __restrict__ state,
    const float* __restrict__ partial,
    const float* __restrict__ W,
    const float* __restrict__ bias,
    float* __restrict__ out, int n)
{
    const int i = (blockIdx.x * blockDim.x + threadIdx.x) * 4;
    if (i >= n) return;
    const int b   = i >> NB_SHIFT;
    const int loc = i & (RANGE - 1);
    const float* pb = partial + (size_t)b * BPB * RANGE + loc;
    fv4 s = {0.f, 0.f, 0.f, 0.f};
    #pragma unroll
    for (int g = 0; g < BPB; ++g)
        s += *(const fv4*)(pb + (size_t)g * RANGE);
    const float w0 = W[0], w1 = W[1], bb = bias[0];
    fv4 st = *(const fv4*)(state + i);
    fv4 o;
    #pragma unroll
    for (int k = 0; k < 4; ++k) o[k] = fmaf(st[k], w0, fmaf(s[k], w1, bb));
    *(fv4*)(out + i) = o;
}

// ---------------- fallback (ws too small): atomic scatter ----------------
__global__ __launch_bounds__(256) void gnn_zero(float4* __restrict__ ws, int n4) {
    int i = blockIdx.x * blockDim.x + threadIdx.x;
    int stride = gridDim.x * blockDim.x;
    const float4 z = make_float4(0.f, 0.f, 0.f, 0.f);
    for (; i < n4; i += stride) ws[i] = z;
}

__global__ __launch_bounds__(256) void gnn_scatter_dev(const float* __restrict__ state,
                                                       const int* __restrict__ src,
                                                       const int* __restrict__ dst,
                                                       float* __restrict__ nsum,
                                                       int n_edges) {
    const int tid = blockIdx.x * blockDim.x + threadIdx.x;
    const int stride = gridDim.x * blockDim.x;
    const int n4 = n_edges >> 2;
    const int4* __restrict__ src4 = (const int4*)src;
    const int4* __restrict__ dst4 = (const int4*)dst;
    for (int i = tid; i < n4; i += stride) {
        int4 s = src4[i];
        int4 d = dst4[i];
        atomicAdd(&nsum[d.x], state[s.x]);
        atomicAdd(&nsum[d.y], state[s.y]);
        atomicAdd(&nsum[d.z], state[s.z]);
        atomicAdd(&nsum[d.w], state[s.w]);
    }
    for (int i = (n4 << 2) + tid; i < n_edges; i += stride)
        atomicAdd(&nsum[dst[i]], state[src[i]]);
}

__global__ __launch_bounds__(256) void gnn_finalize_flat(const float* __restrict__ state,
                                                         const float* __restrict__ nsum,
                                                         const float* __restrict__ W,
                                                         const float* __restrict__ b,
                                                         float* __restrict__ out, int n) {
    int i = blockIdx.x * blockDim.x + threadIdx.x;
    if (i < n) out[i] = fmaf(state[i], W[0], fmaf(nsum[i], W[1], b[0]));
}

extern "C" void kernel_launch(void* const* d_in, const int* in_sizes, int n_in,
                              void* d_out, int out_size, void* d_ws, size_t ws_size,
                              hipStream_t stream) {
    const float* state = (const float*)d_in[0];
    const int*   esrc  = (const int*)d_in[1];
    const int*   edst  = (const int*)d_in[2];
    const float* W     = (const float*)d_in[3];
    const float* b     = (const float*)d_in[4];
    float* out = (float*)d_out;

    const int n_nodes = in_sizes[0];   // 1,000,000
    const int n_edges = in_sizes[1];   // 32,000,000

    const int nbused = (n_nodes + RANGE - 1) >> NB_SHIFT;              // 62
    const long long lamR = (long long)n_edges * RANGE / n_nodes / NREP; // ~131072
    int capR = (int)(lamR + lamR / 8 + 8192);                          // slack + even-pad
    capR = (capR + 3) & ~3;

    const size_t shOff   = 0;
    const size_t shBytes = ((size_t)n_nodes * 2 + 255) & ~(size_t)255;
    const size_t recOff  = shBytes;
    const size_t recBytes= ((size_t)NBALL * NREP * capR * 4 + 255) & ~(size_t)255;
    const size_t curOff  = recOff + recBytes;
    const size_t curBytes= (256 * sizeof(int) + 255) & ~(size_t)255;
    const size_t parOff  = curOff + curBytes;
    const size_t parBytes= (size_t)nbused * BPB * RANGE * sizeof(float);
    const size_t need    = parOff + parBytes;

    if (ws_size >= need && (n_nodes & 3) == 0 && (n_edges & 3) == 0) {
        unsigned short* sh = (unsigned short*)((char*)d_ws + shOff);
        unsigned* records  = (unsigned*)((char*)d_ws + recOff);
        int*      cursors  = (int*)((char*)d_ws + curOff);
        float*    partial  = (float*)((char*)d_ws + parOff);

        k_init_cursors<<<1, 256, 0, stream>>>(cursors);
        k_cvt<<<(n_nodes / 4 + 255) / 256, 256, 0, stream>>>(state, sh, n_nodes / 4);

        int tiles = (n_edges + TILE - 1) / TILE;                       // 7813
        k_partition<<<tiles, TPB, 0, stream>>>(sh, esrc, edst,
                                               records, cursors, n_edges, capR);

        k_bins<<<nbused * BPB, 1024, 0, stream>>>(records, cursors, partial, capR);

        int blocks = (n_nodes / 4 + 255) / 256;
        k_finalize<<<blocks, 256, 0, stream>>>(state, partial, W, b, out, n_nodes);
    } else {
        // fallback: device-scope atomic scatter (needs only 4 MB ws)
        float* nsum = (float*)d_ws;
        int n4n = n_nodes >> 2;
        int zb = (n4n + 255) / 256; if (zb > 2048) zb = 2048;
        gnn_zero<<<zb, 256, 0, stream>>>((float4*)nsum, n4n);
        int work = n_edges >> 2;
        int sb = (work + 255) / 256; if (sb > 8192) sb = 8192;
        gnn_scatter_dev<<<sb, 256, 0, stream>>>(state, esrc, edst, nsum, n_edges);
        int fb = (n_nodes + 255) / 256;
        gnn_finalize_flat<<<fb, 256, 0, stream>>>(state, nsum, W, b, out, n_nodes);
    }
}